// Round 1
// baseline (2143.633 us; speedup 1.0000x reference)
//
#include <hip/hip_runtime.h>
#include <hip/hip_bf16.h>
#include <stdint.h>

#define H 64
#define NB 32

__device__ __forceinline__ float bf2f(uint16_t v) {
    return __uint_as_float(((uint32_t)v) << 16);
}
__device__ __forceinline__ uint16_t f2bf(float f) {
    uint32_t u = __float_as_uint(f);
    u += 0x7fffu + ((u >> 16) & 1u);   // RNE
    return (uint16_t)(u >> 16);
}

// ---------------- conv1: Cin=3, Cout=64, 3x3 SAME, ReLU, bf16 out ----------
__global__ __launch_bounds__(256) void conv1_k(
    const float* __restrict__ x, const float* __restrict__ w,
    const float* __restrict__ bias, uint16_t* __restrict__ h1)
{
    const int b = blockIdx.y;
    const int tile = blockIdx.x;                 // 16 tiles of 16x16
    const int ty0 = (tile >> 2) * 16, tx0 = (tile & 3) * 16;
    __shared__ float in_s[3][18][18];
    __shared__ float w_s[64 * 27];
    __shared__ float b_s[64];
    const int tid = threadIdx.x;
    for (int i = tid; i < 3 * 18 * 18; i += 256) {
        int c = i / 324, r2 = i % 324, yy = r2 / 18, xx = r2 % 18;
        int gy = ty0 - 1 + yy, gx = tx0 - 1 + xx;
        float v = 0.f;
        if (gy >= 0 && gy < H && gx >= 0 && gx < H)
            v = x[((b * 3 + c) * H + gy) * H + gx];
        in_s[c][yy][xx] = v;
    }
    for (int i = tid; i < 64 * 27; i += 256) w_s[i] = w[b * 64 * 27 + i];
    if (tid < 64) b_s[tid] = bias[b * 64 + tid];
    __syncthreads();
    const int y = tid >> 4, xc = tid & 15;
    float r[27];
    #pragma unroll
    for (int c = 0; c < 3; c++)
        #pragma unroll
        for (int ky = 0; ky < 3; ky++)
            #pragma unroll
            for (int kx = 0; kx < 3; kx++)
                r[(c * 3 + ky) * 3 + kx] = in_s[c][y + ky][xc + kx];
    const int gy = ty0 + y, gx = tx0 + xc;
    for (int oc = 0; oc < 64; oc++) {
        float acc = b_s[oc];
        #pragma unroll
        for (int k = 0; k < 27; k++) acc = fmaf(r[k], w_s[oc * 27 + k], acc);
        acc = fmaxf(acc, 0.f);
        h1[((b * 64 + oc) * H + gy) * H + gx] = f2bf(acc);
    }
}

// -------- convN: 3x3 SAME, ReLU; 16 oc x (16 rows x 64 cols) per block -----
// POOL=true: skip activation store, emit per-(b,oc,stripe) spatial sums.
template<int CIN, bool POOL>
__global__ __launch_bounds__(256) void convN_k(
    const uint16_t* __restrict__ in, const float* __restrict__ w,
    const float* __restrict__ bias, uint16_t* __restrict__ out,
    float* __restrict__ partial, const int COUT)
{
    const int b = blockIdx.z;
    const int ocbase = blockIdx.y * 16;
    const int stripe = blockIdx.x;               // rows [stripe*16, +16)
    __shared__ float in_s[2][18][66];
    __shared__ float w_s[16 * 2 * 9];
    __shared__ float red[4][16];
    const int tid = threadIdx.x;
    const int y = tid >> 4, tx = tid & 15, x0 = tx * 4;
    float acc[16][4];
    #pragma unroll
    for (int o = 0; o < 16; o++) {
        float bv = bias[b * COUT + ocbase + o];
        #pragma unroll
        for (int j = 0; j < 4; j++) acc[o][j] = bv;
    }
    for (int ci0 = 0; ci0 < CIN; ci0 += 2) {
        // stage 2 input channels with halo: rows [stripe*16-1, +18), cols [-1, 65)
        for (int i = tid; i < 2 * 18 * 66; i += 256) {
            int ci = i / 1188, r2 = i % 1188, yy = r2 / 66, xx = r2 % 66;
            int gy = stripe * 16 - 1 + yy, gx = xx - 1;
            float v = 0.f;
            if (gy >= 0 && gy < H && gx >= 0 && gx < H)
                v = bf2f(in[((b * CIN + ci0 + ci) * H + gy) * H + gx]);
            in_s[ci][yy][xx] = v;
        }
        // weights [oc][ci][k]
        for (int i = tid; i < 16 * 2 * 9; i += 256) {
            int oc = i / 18, r2 = i % 18, ci = r2 / 9, k = r2 % 9;
            w_s[i] = w[((b * COUT + ocbase + oc) * CIN + ci0 + ci) * 9 + k];
        }
        __syncthreads();
        #pragma unroll
        for (int ci = 0; ci < 2; ci++) {
            float rin[3][6];
            #pragma unroll
            for (int ky = 0; ky < 3; ky++)
                #pragma unroll
                for (int j = 0; j < 6; j++)
                    rin[ky][j] = in_s[ci][y + ky][x0 + j];
            #pragma unroll
            for (int o = 0; o < 16; o++) {
                float wv[9];
                #pragma unroll
                for (int k = 0; k < 9; k++) wv[k] = w_s[o * 18 + ci * 9 + k];
                #pragma unroll
                for (int ky = 0; ky < 3; ky++)
                    #pragma unroll
                    for (int kx = 0; kx < 3; kx++)
                        #pragma unroll
                        for (int j = 0; j < 4; j++)
                            acc[o][j] = fmaf(rin[ky][kx + j], wv[ky * 3 + kx], acc[o][j]);
            }
        }
        __syncthreads();
    }
    #pragma unroll
    for (int o = 0; o < 16; o++)
        #pragma unroll
        for (int j = 0; j < 4; j++) acc[o][j] = fmaxf(acc[o][j], 0.f);

    if (!POOL) {
        const int gy = stripe * 16 + y;
        #pragma unroll
        for (int o = 0; o < 16; o++) {
            ushort4 p;
            p.x = f2bf(acc[o][0]); p.y = f2bf(acc[o][1]);
            p.z = f2bf(acc[o][2]); p.w = f2bf(acc[o][3]);
            *reinterpret_cast<ushort4*>(
                &out[((b * COUT + ocbase + o) * H + gy) * H + x0]) = p;
        }
    } else {
        float s[16];
        #pragma unroll
        for (int o = 0; o < 16; o++) {
            float v = acc[o][0] + acc[o][1] + acc[o][2] + acc[o][3];
            #pragma unroll
            for (int off = 32; off > 0; off >>= 1) v += __shfl_xor(v, off, 64);
            s[o] = v;
        }
        const int wave = tid >> 6, lane = tid & 63;
        if (lane == 0) {
            #pragma unroll
            for (int o = 0; o < 16; o++) red[wave][o] = s[o];
        }
        __syncthreads();
        if (tid < 16) {
            float t = red[0][tid] + red[1][tid] + red[2][tid] + red[3][tid];
            partial[(b * COUT + ocbase + tid) * 4 + stripe] = t;
        }
    }
}

// ------- pooled mean + outer product with fc weight + bias4 ----------------
__global__ void fc_k(const float* __restrict__ partial,
                     const float* __restrict__ fcw,
                     const float* __restrict__ b4, float* __restrict__ out)
{
    const int b = blockIdx.x, c = threadIdx.x;   // 32 x 256
    const float* p = partial + (b * 256 + c) * 4;
    float pooled = (p[0] + p[1] + p[2] + p[3]) * (1.f / 4096.f);
    #pragma unroll
    for (int o = 0; o < 10; o++)
        out[(b * 256 + c) * 10 + o] = fmaf(pooled, fcw[b * 10 + o], b4[b * 10 + o]);
}

extern "C" void kernel_launch(void* const* d_in, const int* in_sizes, int n_in,
                              void* d_out, int out_size, void* d_ws, size_t ws_size,
                              hipStream_t stream)
{
    const float* x   = (const float*)d_in[0];
    const float* w1  = (const float*)d_in[1];
    const float* w2  = (const float*)d_in[2];
    const float* w3  = (const float*)d_in[3];
    const float* fcw = (const float*)d_in[4];
    const float* b1  = (const float*)d_in[5];
    const float* b2  = (const float*)d_in[6];
    const float* b3  = (const float*)d_in[7];
    const float* b4  = (const float*)d_in[8];
    char* ws = (char*)d_ws;
    uint16_t* h1   = (uint16_t*)ws;                               // 16 MB: (32,64,64,64) bf16
    uint16_t* h2   = (uint16_t*)(ws + (size_t)16 * 1024 * 1024);  // 32 MB: (32,128,64,64) bf16
    float* partial = (float*)(ws + (size_t)48 * 1024 * 1024);     // 128 KB: (32,256,4) f32

    conv1_k<<<dim3(16, NB), 256, 0, stream>>>(x, w1, b1, h1);
    convN_k<64, false><<<dim3(4, 8, NB), 256, 0, stream>>>(h1, w2, b2, h2, nullptr, 128);
    convN_k<128, true><<<dim3(4, 16, NB), 256, 0, stream>>>(h2, w3, b3, nullptr, partial, 256);
    fc_k<<<NB, 256, 0, stream>>>(partial, fcw, b4, (float*)d_out);
}

// Round 2
// 238.309 us; speedup vs baseline: 8.9952x; 8.9952x over previous
//
#include <hip/hip_runtime.h>
#include <stdint.h>

typedef __attribute__((ext_vector_type(8))) short short8;
typedef __attribute__((ext_vector_type(16))) float f32x16;

#define NB 32

__device__ __forceinline__ float bf2f(uint16_t v) {
    return __uint_as_float(((uint32_t)v) << 16);
}
__device__ __forceinline__ uint16_t f2bf(float f) {
    uint32_t u = __float_as_uint(f);
    u += 0x7fffu + ((u >> 16) & 1u);   // RNE
    return (uint16_t)(u >> 16);
}

// ---------------- conv1: Cin=3, Cout=64, 3x3 SAME, ReLU, NHWC bf16 out -----
__global__ __launch_bounds__(256) void conv1_k(
    const float* __restrict__ x, const float* __restrict__ w,
    const float* __restrict__ bias, uint16_t* __restrict__ h1)
{
    const int b = blockIdx.y;
    const int tile = blockIdx.x;                 // 16 tiles of 16x16
    const int ty0 = (tile >> 2) * 16, tx0 = (tile & 3) * 16;
    __shared__ float in_s[3][18][18];
    __shared__ float w_s[64 * 27];
    __shared__ float b_s[64];
    const int tid = threadIdx.x;
    for (int i = tid; i < 3 * 18 * 18; i += 256) {
        int c = i / 324, r2 = i % 324, yy = r2 / 18, xx = r2 % 18;
        int gy = ty0 - 1 + yy, gx = tx0 - 1 + xx;
        float v = 0.f;
        if (gy >= 0 && gy < 64 && gx >= 0 && gx < 64)
            v = x[((b * 3 + c) * 64 + gy) * 64 + gx];
        in_s[c][yy][xx] = v;
    }
    for (int i = tid; i < 64 * 27; i += 256) w_s[i] = w[b * 64 * 27 + i];
    if (tid < 64) b_s[tid] = bias[b * 64 + tid];
    __syncthreads();
    const int y = tid >> 4, xc = tid & 15;
    float r[27];
    #pragma unroll
    for (int c = 0; c < 3; c++)
        #pragma unroll
        for (int ky = 0; ky < 3; ky++)
            #pragma unroll
            for (int kx = 0; kx < 3; kx++)
                r[(c * 3 + ky) * 3 + kx] = in_s[c][y + ky][xc + kx];
    const int gy = ty0 + y, gx = tx0 + xc;
    uint16_t* dst = h1 + ((size_t)(b * 4096 + gy * 64 + gx)) * 64;
    for (int oc0 = 0; oc0 < 64; oc0 += 4) {
        float a4[4];
        #pragma unroll
        for (int u = 0; u < 4; u++) {
            float acc = b_s[oc0 + u];
            #pragma unroll
            for (int k = 0; k < 27; k++) acc = fmaf(r[k], w_s[(oc0 + u) * 27 + k], acc);
            a4[u] = fmaxf(acc, 0.f);
        }
        ushort4 p;
        p.x = f2bf(a4[0]); p.y = f2bf(a4[1]); p.z = f2bf(a4[2]); p.w = f2bf(a4[3]);
        *reinterpret_cast<ushort4*>(dst + oc0) = p;
    }
}

// ------- weight prep: w[b][oc][ci][3][3] f32 -> wp[b][kk][oc][ci] bf16 -----
template<int COUT, int CIN>
__global__ __launch_bounds__(256) void prep_w(
    const float* __restrict__ w, uint16_t* __restrict__ wp)
{
    const int idx = blockIdx.x * 256 + threadIdx.x;
    constexpr int total = NB * COUT * CIN;
    if (idx >= total) return;
    const int ci = idx % CIN;
    const int t  = idx / CIN;
    const int oc = t % COUT;
    const int b  = t / COUT;
    const float* s = w + (size_t)idx * 9;
    #pragma unroll
    for (int k = 0; k < 9; k++)
        wp[((size_t)(b * 9 + k) * COUT + oc) * CIN + ci] = f2bf(s[k]);
}

// ---------------- MFMA implicit-GEMM conv, 3x3 SAME, ReLU ------------------
// Block: 64 oc x 4 rows (4 waves, one row each). Per wave: 2 px-frags x 2
// oc-frags of v_mfma_f32_32x32x16_bf16, K-loop over ci in chunks of 32.
// A = input (M=px), B = weights (N=oc)  ->  D[px][oc]: col = lane&31 = oc.
// LDS in_s[6 rows][66 px][32 ci] bf16, slot-swizzled ^(px&3); w_s[9][64][32]
// swizzled ^(oc&3). POOL=true fuses global mean-pool partials.
template<int CIN, int COUT, bool POOL>
__global__ __launch_bounds__(256, 2) void conv_mfma(
    const uint16_t* __restrict__ in, const uint16_t* __restrict__ wp,
    const float* __restrict__ bias, uint16_t* __restrict__ out,
    float* __restrict__ partial)
{
    constexpr int IN_B = 6 * 66 * 64;   // 25344 B
    constexpr int W_B  = 9 * 64 * 64;   // 36864 B
    __shared__ __align__(16) char sm[IN_B + W_B + 4 * 64 * 4];
    const int b = blockIdx.z;
    const int ocbase = blockIdx.y * 64;
    const int y0 = blockIdx.x * 4;
    const int tid = threadIdx.x;
    const int w4 = tid >> 6;            // wave id = row within block
    const int l  = tid & 63;
    const int q  = l >> 5;
    const int ln = l & 31;

    f32x16 acc[2][2];
    #pragma unroll
    for (int ni = 0; ni < 2; ni++) {
        float bv = bias[b * COUT + ocbase + ni * 32 + ln];
        #pragma unroll
        for (int mi = 0; mi < 2; mi++)
            #pragma unroll
            for (int r = 0; r < 16; r++) acc[mi][ni][r] = bv;
    }

    // Per-lane LDS fragment pointers (constant across K-steps).
    const char* pa[3][2];
    #pragma unroll
    for (int kx = 0; kx < 3; kx++)
        #pragma unroll
        for (int kc = 0; kc < 2; kc++)
            pa[kx][kc] = sm + w4 * 4224 + (ln + kx) * 64
                         + 16 * ((kc * 2 + q) ^ ((ln + kx) & 3));
    const char* pb[2];
    #pragma unroll
    for (int kc = 0; kc < 2; kc++)
        pb[kc] = sm + IN_B + ln * 64 + 16 * ((kc * 2 + q) ^ (ln & 3));

    for (int ci0 = 0; ci0 < CIN; ci0 += 32) {
        // stage input: rows y0-1..y0+4, cols -1..64, 32 ci (bf16, swizzled)
        for (int c = tid; c < 6 * 66 * 4; c += 256) {
            const int slot = c & 3, site = c >> 2;
            const int row = site / 66, px = site - row * 66;
            const int gy = y0 - 1 + row, gx = px - 1;
            short8 v = {0, 0, 0, 0, 0, 0, 0, 0};
            if ((unsigned)gy < 64u && (unsigned)gx < 64u)
                v = *(const short8*)(in + ((size_t)((b * 64 + gy) * 64 + gx) * CIN
                                           + ci0 + slot * 8));
            *(short8*)(sm + row * 4224 + px * 64 + 16 * (slot ^ (px & 3))) = v;
        }
        // stage weights: [kk][oc 0..63][ci chunk]
        for (int c = tid; c < 9 * 64 * 4; c += 256) {
            const int slot = c & 3, oc = (c >> 2) & 63, kk = c >> 8;
            short8 v = *(const short8*)(wp + ((size_t)(b * 9 + kk) * COUT
                                              + ocbase + oc) * CIN + ci0 + slot * 8);
            *(short8*)(sm + IN_B + kk * 4096 + oc * 64 + 16 * (slot ^ (oc & 3))) = v;
        }
        __syncthreads();
        #pragma unroll
        for (int ky = 0; ky < 3; ky++)
            #pragma unroll
            for (int kx = 0; kx < 3; kx++) {
                const int kk = ky * 3 + kx;
                #pragma unroll
                for (int kc = 0; kc < 2; kc++) {
                    short8 a0 = *(const short8*)(pa[kx][kc] + ky * 4224);
                    short8 a1 = *(const short8*)(pa[kx][kc] + ky * 4224 + 2048);
                    short8 b0 = *(const short8*)(pb[kc] + kk * 4096);
                    short8 b1 = *(const short8*)(pb[kc] + kk * 4096 + 2048);
                    acc[0][0] = __builtin_amdgcn_mfma_f32_32x32x16_bf16(a0, b0, acc[0][0], 0, 0, 0);
                    acc[0][1] = __builtin_amdgcn_mfma_f32_32x32x16_bf16(a0, b1, acc[0][1], 0, 0, 0);
                    acc[1][0] = __builtin_amdgcn_mfma_f32_32x32x16_bf16(a1, b0, acc[1][0], 0, 0, 0);
                    acc[1][1] = __builtin_amdgcn_mfma_f32_32x32x16_bf16(a1, b1, acc[1][1], 0, 0, 0);
                }
            }
        __syncthreads();
    }

    if (!POOL) {
        const int y = y0 + w4;
        #pragma unroll
        for (int mi = 0; mi < 2; mi++)
            #pragma unroll
            for (int ni = 0; ni < 2; ni++)
                #pragma unroll
                for (int r = 0; r < 16; r++) {
                    float v = fmaxf(acc[mi][ni][r], 0.f);
                    const int px = mi * 32 + (r & 3) + 8 * (r >> 2) + 4 * q;
                    out[(size_t)((b * 64 + y) * 64 + px) * COUT
                        + ocbase + ni * 32 + ln] = f2bf(v);
                }
    } else {
        float* red = (float*)(sm + IN_B + W_B);
        #pragma unroll
        for (int ni = 0; ni < 2; ni++) {
            float s = 0.f;
            #pragma unroll
            for (int mi = 0; mi < 2; mi++)
                #pragma unroll
                for (int r = 0; r < 16; r++) s += fmaxf(acc[mi][ni][r], 0.f);
            s += __shfl_xor(s, 32);       // combine q halves -> full 64-px row sum
            if (q == 0) red[w4 * 64 + ni * 32 + ln] = s;
        }
        __syncthreads();
        if (tid < 64) {
            float t = red[tid] + red[64 + tid] + red[128 + tid] + red[192 + tid];
            partial[(size_t)(b * 256 + ocbase + tid) * 16 + blockIdx.x] = t;
        }
    }
}

// ------- pooled mean + outer product with fc weight + bias4 ----------------
__global__ void fc_k(const float* __restrict__ partial,
                     const float* __restrict__ fcw,
                     const float* __restrict__ b4, float* __restrict__ out)
{
    const int b = blockIdx.x, c = threadIdx.x;   // 32 x 256
    const float* p = partial + (size_t)(b * 256 + c) * 16;
    float s = 0.f;
    #pragma unroll
    for (int i = 0; i < 16; i++) s += p[i];
    const float pooled = s * (1.f / 4096.f);
    #pragma unroll
    for (int o = 0; o < 10; o++)
        out[(b * 256 + c) * 10 + o] = fmaf(pooled, fcw[b * 10 + o], b4[b * 10 + o]);
}

extern "C" void kernel_launch(void* const* d_in, const int* in_sizes, int n_in,
                              void* d_out, int out_size, void* d_ws, size_t ws_size,
                              hipStream_t stream)
{
    const float* x   = (const float*)d_in[0];
    const float* w1  = (const float*)d_in[1];
    const float* w2  = (const float*)d_in[2];
    const float* w3  = (const float*)d_in[3];
    const float* fcw = (const float*)d_in[4];
    const float* b1  = (const float*)d_in[5];
    const float* b2  = (const float*)d_in[6];
    const float* b3  = (const float*)d_in[7];
    const float* b4  = (const float*)d_in[8];
    char* ws = (char*)d_ws;
    // Lifetime-aliased layout (peak 55,050,240 B):
    //   h2  [0, 32M)                 (32,4096,128) bf16, live conv2..conv3
    //   h1  [32M, 48M)               (32,4096,64)  bf16, live conv1..conv2
    //   wp2 [48M, 52.5M)             bf16 transposed w2, live prep2..conv2
    //   wp3 [32M, 50M)   (over dead h1+wp2) written AFTER conv2
    //   partial [50M, 50.5M)         (32,256,16) f32, written by conv3
    uint16_t* h2      = (uint16_t*)(ws);
    uint16_t* h1      = (uint16_t*)(ws + 33554432);
    uint16_t* wp2     = (uint16_t*)(ws + 50331648);
    uint16_t* wp3     = (uint16_t*)(ws + 33554432);
    float*    partial = (float*)   (ws + 52428800);

    prep_w<128, 64><<<1024, 256, 0, stream>>>(w2, wp2);
    conv1_k<<<dim3(16, NB), 256, 0, stream>>>(x, w1, b1, h1);
    conv_mfma<64, 128, false><<<dim3(16, 2, NB), 256, 0, stream>>>(h1, wp2, b2, h2, nullptr);
    prep_w<256, 128><<<4096, 256, 0, stream>>>(w3, wp3);   // after conv2: h1/wp2 dead
    conv_mfma<128, 256, true><<<dim3(16, 4, NB), 256, 0, stream>>>(h2, wp3, b3, nullptr, partial);
    fc_k<<<NB, 256, 0, stream>>>(partial, fcw, b4, (float*)d_out);
}

// Round 3
// 184.569 us; speedup vs baseline: 11.6143x; 1.2912x over previous
//
#include <hip/hip_runtime.h>
#include <stdint.h>

typedef __attribute__((ext_vector_type(8))) short short8;
typedef __attribute__((ext_vector_type(16))) float f32x16;

#define NB 32

__device__ __forceinline__ float bf2f(uint16_t v) {
    return __uint_as_float(((uint32_t)v) << 16);
}
__device__ __forceinline__ uint16_t f2bf(float f) {
    uint32_t u = __float_as_uint(f);
    u += 0x7fffu + ((u >> 16) & 1u);   // RNE
    return (uint16_t)(u >> 16);
}

// async global(16B) -> LDS, linear dest (wave-uniform base + lane*16)
__device__ __forceinline__ void gload16(const void* g, void* l) {
    __builtin_amdgcn_global_load_lds(
        (const __attribute__((address_space(1))) uint32_t*)g,
        (__attribute__((address_space(3))) uint32_t*)l, 16, 0, 0);
}

// ---------------- conv1: Cin=3, Cout=64, 3x3 SAME, ReLU, NHWC bf16 out -----
__global__ __launch_bounds__(256) void conv1_k(
    const float* __restrict__ x, const float* __restrict__ w,
    const float* __restrict__ bias, uint16_t* __restrict__ h1)
{
    const int b = blockIdx.y;
    const int tile = blockIdx.x;                 // 16 tiles of 16x16
    const int ty0 = (tile >> 2) * 16, tx0 = (tile & 3) * 16;
    __shared__ float in_s[3][18][18];
    __shared__ float w_s[64 * 27];
    __shared__ float b_s[64];
    const int tid = threadIdx.x;
    for (int i = tid; i < 3 * 18 * 18; i += 256) {
        int c = i / 324, r2 = i % 324, yy = r2 / 18, xx = r2 % 18;
        int gy = ty0 - 1 + yy, gx = tx0 - 1 + xx;
        float v = 0.f;
        if (gy >= 0 && gy < 64 && gx >= 0 && gx < 64)
            v = x[((b * 3 + c) * 64 + gy) * 64 + gx];
        in_s[c][yy][xx] = v;
    }
    for (int i = tid; i < 64 * 27; i += 256) w_s[i] = w[b * 64 * 27 + i];
    if (tid < 64) b_s[tid] = bias[b * 64 + tid];
    __syncthreads();
    const int y = tid >> 4, xc = tid & 15;
    float r[27];
    #pragma unroll
    for (int c = 0; c < 3; c++)
        #pragma unroll
        for (int ky = 0; ky < 3; ky++)
            #pragma unroll
            for (int kx = 0; kx < 3; kx++)
                r[(c * 3 + ky) * 3 + kx] = in_s[c][y + ky][xc + kx];
    const int gy = ty0 + y, gx = tx0 + xc;
    uint16_t* dst = h1 + ((size_t)(b * 4096 + gy * 64 + gx)) * 64;
    for (int oc0 = 0; oc0 < 64; oc0 += 4) {
        float a4[4];
        #pragma unroll
        for (int u = 0; u < 4; u++) {
            float acc = b_s[oc0 + u];
            #pragma unroll
            for (int k = 0; k < 27; k++) acc = fmaf(r[k], w_s[(oc0 + u) * 27 + k], acc);
            a4[u] = fmaxf(acc, 0.f);
        }
        ushort4 p;
        p.x = f2bf(a4[0]); p.y = f2bf(a4[1]); p.z = f2bf(a4[2]); p.w = f2bf(a4[3]);
        *reinterpret_cast<ushort4*>(dst + oc0) = p;
    }
}

// ------- weight prep: w[b][oc][ci][3][3] f32 -> wp[b][kk][oc][ci] bf16 -----
template<int COUT, int CIN>
__global__ __launch_bounds__(256) void prep_w(
    const float* __restrict__ w, uint16_t* __restrict__ wp)
{
    const int idx = blockIdx.x * 256 + threadIdx.x;
    constexpr int total = NB * COUT * CIN;
    if (idx >= total) return;
    const int ci = idx % CIN;
    const int t  = idx / CIN;
    const int oc = t % COUT;
    const int b  = t / COUT;
    const float* s = w + (size_t)idx * 9;
    #pragma unroll
    for (int k = 0; k < 9; k++)
        wp[((size_t)(b * 9 + k) * COUT + oc) * CIN + ci] = f2bf(s[k]);
}

// ---------------- MFMA implicit-GEMM conv, 3x3 SAME, ReLU ------------------
// Block: 64 oc x 4 rows (4 waves, one row each); per wave 2x2 frags of
// v_mfma_f32_32x32x16_bf16. K-step = 16 ci. Double-buffered LDS staged via
// global_load_lds(16B) with sigma-swizzled SOURCE addresses (linear dest);
// reads apply the same sigma: g' = g ^ ((g>>3)&7) on 16B granules.
// Input tile rows padded to 68 sites (136 granules, mult. of 8) so row
// strides preserve granule bits 0-2. Halo/pad lanes load from zero page.
template<int CIN, int COUT, bool POOL>
__global__ __launch_bounds__(256, 2) void conv_mfma(
    const uint16_t* __restrict__ in, const uint16_t* __restrict__ wp,
    const float* __restrict__ bias, uint16_t* __restrict__ out,
    float* __restrict__ partial, const float* __restrict__ zp)
{
    constexpr int IN_GA = 832;               // 6*68*2 = 816 valid, pad to 832
    constexpr int W_G   = 1152;              // 9*64*2
    constexpr int W_OFF = IN_GA * 16;        // 13312 B
    constexpr int BUF_B = W_OFF + W_G * 16;  // 31744 B
    __shared__ __align__(16) char sm[2 * BUF_B + 1024];   // 64512 B
    const int b = blockIdx.z;
    const int ocbase = blockIdx.y * 64;
    const int y0 = blockIdx.x * 4;
    const int tid = threadIdx.x;
    const int wv = tid >> 6, l = tid & 63, q = l >> 5, ln = l & 31;
    const int NK = CIN / 16;

    // ---- per-lane staging source pointers (sigma-swizzled), computed once
    const uint16_t* src_in[4];
    #pragma unroll
    for (int i = 0; i < 4; i++) {
        const int gp = i * 256 + tid;
        const int g = gp ^ ((gp >> 3) & 7);
        const int qq = g & 1, site = g >> 1;
        const int row = site / 68, px = site - row * 68;
        const int gy = y0 - 1 + row, gx = px - 1;
        const bool valid = (px < 66) && ((unsigned)gy < 64u) && ((unsigned)gx < 64u);
        src_in[i] = valid ? in + ((size_t)((b * 64 + gy) * 64 + gx) * CIN + qq * 8)
                          : (const uint16_t*)zp;
    }
    const uint16_t* src_w[5];
    #pragma unroll
    for (int i = 0; i < 5; i++) {
        const int gp = i * 256 + tid;
        const int g = gp ^ ((gp >> 3) & 7);
        const int qq = g & 1, kk = g >> 7, oc = (g >> 1) & 63;
        src_w[i] = wp + ((size_t)(b * 9 + kk) * COUT + ocbase + oc) * CIN + qq * 8;
    }

    // ---- per-lane swizzled LDS read offsets (byte, within one buffer)
    int aoff[3][3][2];
    #pragma unroll
    for (int ky = 0; ky < 3; ky++)
        #pragma unroll
        for (int kx = 0; kx < 3; kx++)
            #pragma unroll
            for (int m = 0; m < 2; m++) {
                const int px = m * 32 + ln + kx;
                const int g = ((wv + ky) * 68 + px) * 2 + q;
                aoff[ky][kx][m] = (g ^ ((g >> 3) & 7)) * 16;
            }
    const int gb = ln * 2 + q;
    const int boff0 = (gb ^ ((gb >> 3) & 7)) * 16;   // n=1 is boff0+1024 (bit6)

    f32x16 acc00, acc01, acc10, acc11;
    {
        const float bv0 = bias[b * COUT + ocbase + ln];
        const float bv1 = bias[b * COUT + ocbase + 32 + ln];
        #pragma unroll
        for (int r = 0; r < 16; r++) {
            acc00[r] = bv0; acc10[r] = bv0;
            acc01[r] = bv1; acc11[r] = bv1;
        }
    }

    // ---- staging: one K-step (16 ci) into buffer `base`
    auto stage = [&](char* base, int k) {
        const int koff = k * 16;
        #pragma unroll
        for (int i = 0; i < 4; i++) {
            const int g0 = i * 256 + wv * 64;
            if (g0 < IN_GA)
                gload16(src_in[i] + koff, base + g0 * 16);
        }
        #pragma unroll
        for (int i = 0; i < 5; i++) {
            const int g0 = i * 256 + wv * 64;
            if (g0 < W_G)
                gload16(src_w[i] + koff, base + W_OFF + g0 * 16);
        }
    };

    stage(sm, 0);
    asm volatile("s_waitcnt vmcnt(0)" ::: "memory");
    __syncthreads();

    for (int k = 0; k < NK; k++) {
        const char* cb = sm + (k & 1) * BUF_B;
        if (k + 1 < NK) stage(sm + ((k + 1) & 1) * BUF_B, k + 1);
        #pragma unroll
        for (int ky = 0; ky < 3; ky++)
            #pragma unroll
            for (int kx = 0; kx < 3; kx++) {
                const char* bw = cb + W_OFF + (ky * 3 + kx) * 2048;
                short8 b0 = *(const short8*)(bw + boff0);
                short8 b1 = *(const short8*)(bw + boff0 + 1024);
                short8 a0 = *(const short8*)(cb + aoff[ky][kx][0]);
                short8 a1 = *(const short8*)(cb + aoff[ky][kx][1]);
                acc00 = __builtin_amdgcn_mfma_f32_32x32x16_bf16(a0, b0, acc00, 0, 0, 0);
                acc01 = __builtin_amdgcn_mfma_f32_32x32x16_bf16(a0, b1, acc01, 0, 0, 0);
                acc10 = __builtin_amdgcn_mfma_f32_32x32x16_bf16(a1, b0, acc10, 0, 0, 0);
                acc11 = __builtin_amdgcn_mfma_f32_32x32x16_bf16(a1, b1, acc11, 0, 0, 0);
            }
        asm volatile("s_waitcnt vmcnt(0)" ::: "memory");
        __syncthreads();
    }

    if (!POOL) {
        const int y = y0 + wv;
        #pragma unroll
        for (int r = 0; r < 16; r++) {
            const int pxr = (r & 3) + 8 * (r >> 2) + 4 * q;
            uint16_t* d0 = out + (size_t)((b * 64 + y) * 64 + pxr) * COUT + ocbase;
            uint16_t* d1 = out + (size_t)((b * 64 + y) * 64 + 32 + pxr) * COUT + ocbase;
            d0[ln]      = f2bf(fmaxf(acc00[r], 0.f));
            d0[32 + ln] = f2bf(fmaxf(acc01[r], 0.f));
            d1[ln]      = f2bf(fmaxf(acc10[r], 0.f));
            d1[32 + ln] = f2bf(fmaxf(acc11[r], 0.f));
        }
    } else {
        float* red = (float*)(sm + 2 * BUF_B);
        float s0 = 0.f, s1 = 0.f;
        #pragma unroll
        for (int r = 0; r < 16; r++) {
            s0 += fmaxf(acc00[r], 0.f) + fmaxf(acc10[r], 0.f);
            s1 += fmaxf(acc01[r], 0.f) + fmaxf(acc11[r], 0.f);
        }
        s0 += __shfl_xor(s0, 32);
        s1 += __shfl_xor(s1, 32);
        if (q == 0) {
            red[wv * 64 + ln] = s0;
            red[wv * 64 + 32 + ln] = s1;
        }
        __syncthreads();
        if (tid < 64) {
            float t = red[tid] + red[64 + tid] + red[128 + tid] + red[192 + tid];
            partial[(size_t)(b * 256 + ocbase + tid) * 16 + blockIdx.x] = t;
        }
    }
}

// ------- pooled mean + outer product with fc weight + bias4 ----------------
__global__ void fc_k(const float* __restrict__ partial,
                     const float* __restrict__ fcw,
                     const float* __restrict__ b4, float* __restrict__ out)
{
    const int b = blockIdx.x, c = threadIdx.x;   // 32 x 256
    const float* p = partial + (size_t)(b * 256 + c) * 16;
    float s = 0.f;
    #pragma unroll
    for (int i = 0; i < 16; i++) s += p[i];
    const float pooled = s * (1.f / 4096.f);
    #pragma unroll
    for (int o = 0; o < 10; o++)
        out[(b * 256 + c) * 10 + o] = fmaf(pooled, fcw[b * 10 + o], b4[b * 10 + o]);
}

extern "C" void kernel_launch(void* const* d_in, const int* in_sizes, int n_in,
                              void* d_out, int out_size, void* d_ws, size_t ws_size,
                              hipStream_t stream)
{
    const float* x   = (const float*)d_in[0];
    const float* w1  = (const float*)d_in[1];
    const float* w2  = (const float*)d_in[2];
    const float* w3  = (const float*)d_in[3];
    const float* fcw = (const float*)d_in[4];
    const float* b1  = (const float*)d_in[5];
    const float* b2  = (const float*)d_in[6];
    const float* b3  = (const float*)d_in[7];
    const float* b4  = (const float*)d_in[8];
    char* ws = (char*)d_ws;
    // Lifetime-aliased layout (peak 55,050,240 B, proven in R2):
    //   h2  [0, 32Mi)        (32,4096,128) bf16, live conv2..conv3
    //   h1  [32Mi, 48Mi)     (32,4096,64)  bf16, live conv1..conv2
    //   wp2 [48Mi, 52.5Mi)   bf16 w2^T, live prep2..conv2
    //   wp3 [32Mi, 50Mi)     (over dead h1+wp2 head) written AFTER conv2
    //   partial [50Mi, +512K) f32, written by conv3
    // zero page = first 64KB of d_out (memset each launch; fc_k rewrites all)
    uint16_t* h2      = (uint16_t*)(ws);
    uint16_t* h1      = (uint16_t*)(ws + 33554432);
    uint16_t* wp2     = (uint16_t*)(ws + 50331648);
    uint16_t* wp3     = (uint16_t*)(ws + 33554432);
    float*    partial = (float*)   (ws + 52428800);
    const float* zp   = (const float*)d_out;

    hipMemsetAsync(d_out, 0, 65536, stream);
    prep_w<128, 64><<<1024, 256, 0, stream>>>(w2, wp2);
    conv1_k<<<dim3(16, NB), 256, 0, stream>>>(x, w1, b1, h1);
    conv_mfma<64, 128, false><<<dim3(16, 2, NB), 256, 0, stream>>>(h1, wp2, b2, h2, nullptr, zp);
    prep_w<256, 128><<<4096, 256, 0, stream>>>(w3, wp3);   // after conv2: h1/wp2 dead
    conv_mfma<128, 256, true><<<dim3(16, 4, NB), 256, 0, stream>>>(h2, wp3, b3, nullptr, partial, zp);
    fc_k<<<NB, 256, 0, stream>>>(partial, fcw, b4, (float*)d_out);
}